// Round 1
// baseline (1122.588 us; speedup 1.0000x reference)
//
#include <hip/hip_runtime.h>
#include <stdint.h>

#define NN 16384
#define EE 8192
#define FT 64

typedef float v4f __attribute__((ext_vector_type(4)));

// v_perm_b32: combined = {hi, lo}, sel byte 0-3 -> lo bytes, 4-7 -> hi bytes
__device__ __forceinline__ uint32_t prm(uint32_t hi, uint32_t lo, uint32_t sel) {
  return __builtin_amdgcn_perm(hi, lo, sel);
}

// pack 4 floats -> 4 fp8 e4m3 bytes (byte0 = a .. byte3 = d)
__device__ __forceinline__ uint32_t pk4(float a, float b, float c, float d) {
  uint32_t lo = __builtin_amdgcn_cvt_pk_fp8_f32(a, b, 0, false);
  return __builtin_amdgcn_cvt_pk_fp8_f32(c, d, lo, true);
}

// ---------------------------------------------------------------------------
// K1: stream H (fp32) once. Produce:
//   rowsum[n] (for dv), colsum[e] (for de),
//   Hn8  [N][E] fp8 (natural, for pass C),
//   H8T  [E][N] fp8 (transposed, for pass B).
// Tile: 64 n-rows x 256 e-cols per block. In-register 4x4 byte transpose via
// v_perm, staged through padded LDS so all global writes are >=16B chunks.
// ---------------------------------------------------------------------------
__global__ __launch_bounds__(256) void k_prep_h(
    const float* __restrict__ H,
    uint8_t* __restrict__ Hn8,
    uint8_t* __restrict__ H8T,
    float* __restrict__ rowsum,
    float* __restrict__ colsum)
{
  __shared__ uint8_t T8[256 * 68];   // [e_local][64 n + 4 pad]
  __shared__ float csumL[256];

  const int t    = threadIdx.x;
  const int lane = t & 63;
  const int wv   = t >> 6;
  const int e0   = blockIdx.x * 256;
  const int n0   = blockIdx.y * 64;

  csumL[t] = 0.f;
  __syncthreads();

  float cs0 = 0.f, cs1 = 0.f, cs2 = 0.f, cs3 = 0.f;

  for (int m = 0; m < 4; ++m) {
    const int g = wv + 4 * m;            // row-group 0..15 (wave-private)
    float4 r[4];
#pragma unroll
    for (int i = 0; i < 4; ++i) {
      const float* p = H + (size_t)(n0 + 4 * g + i) * EE + e0 + 4 * lane;
      r[i] = *(const float4*)p;
    }
    uint32_t D[4];
#pragma unroll
    for (int i = 0; i < 4; ++i) {
      cs0 += r[i].x; cs1 += r[i].y; cs2 += r[i].z; cs3 += r[i].w;
      float rsv = r[i].x + r[i].y + r[i].z + r[i].w;
#pragma unroll
      for (int s = 1; s < 64; s <<= 1) rsv += __shfl_xor(rsv, s);
      if (lane == 0) atomicAdd(&rowsum[n0 + 4 * g + i], rsv);
      D[i] = pk4(r[i].x, r[i].y, r[i].z, r[i].w);
      *(uint32_t*)(Hn8 + (size_t)(n0 + 4 * g + i) * EE + e0 + 4 * lane) = D[i];
    }
    // 4x4 byte transpose: T_b = column b of rows D0..D3
    uint32_t lo01 = prm(D[1], D[0], 0x05010400u);
    uint32_t hi01 = prm(D[1], D[0], 0x07030602u);
    uint32_t lo23 = prm(D[3], D[2], 0x05010400u);
    uint32_t hi23 = prm(D[3], D[2], 0x07030602u);
    uint32_t T0 = prm(lo23, lo01, 0x05040100u);
    uint32_t T1 = prm(lo23, lo01, 0x07060302u);
    uint32_t T2 = prm(hi23, hi01, 0x05040100u);
    uint32_t T3 = prm(hi23, hi01, 0x07060302u);
    *(uint32_t*)&T8[(size_t)(4 * lane + 0) * 68 + 4 * g] = T0;
    *(uint32_t*)&T8[(size_t)(4 * lane + 1) * 68 + 4 * g] = T1;
    *(uint32_t*)&T8[(size_t)(4 * lane + 2) * 68 + 4 * g] = T2;
    *(uint32_t*)&T8[(size_t)(4 * lane + 3) * 68 + 4 * g] = T3;
  }

  atomicAdd(&csumL[4 * lane + 0], cs0);
  atomicAdd(&csumL[4 * lane + 1], cs1);
  atomicAdd(&csumL[4 * lane + 2], cs2);
  atomicAdd(&csumL[4 * lane + 3], cs3);
  __syncthreads();
  atomicAdd(&colsum[e0 + t], csumL[t]);

  // transposed writeout: thread t owns e_local = t (row of 64 n-bytes)
  uint32_t d[16];
#pragma unroll
  for (int j = 0; j < 16; ++j) d[j] = *(const uint32_t*)&T8[(size_t)t * 68 + 4 * j];
  uint8_t* dst = H8T + (size_t)(e0 + t) * NN + n0;
#pragma unroll
  for (int j = 0; j < 4; ++j) {
    uint4 v; v.x = d[4*j]; v.y = d[4*j+1]; v.z = d[4*j+2]; v.w = d[4*j+3];
    *(uint4*)(dst + 16 * j) = v;
  }
}

// ---------------------------------------------------------------------------
// K2: Zt[f][n] = fp8( 64 * rsqrt(rowsum[n]) * (x @ weight)[n][f] )
// (x1 carried at x64 so it sits in e4m3's normal range; /64 folded into K4)
// ---------------------------------------------------------------------------
__global__ __launch_bounds__(256) void k_z(
    const float* __restrict__ x,
    const float* __restrict__ weight,
    const float* __restrict__ rowsum,
    uint8_t* __restrict__ Zt)
{
  __shared__ float wT[64 * 68];   // [f][c], padded stride 68 floats
  const int t  = threadIdx.x;
  const int n0 = blockIdx.x * 64;
  for (int i = t; i < 4096; i += 256) {
    int cc = i >> 6, ff = i & 63;
    wT[ff * 68 + cc] = weight[i];
  }
  __syncthreads();

  const int f  = t >> 2;
  const int ns = (t & 3) * 16;

  float wr[64];
#pragma unroll
  for (int j = 0; j < 16; ++j) {
    float4 w4 = *(const float4*)&wT[f * 68 + 4 * j];
    wr[4*j] = w4.x; wr[4*j+1] = w4.y; wr[4*j+2] = w4.z; wr[4*j+3] = w4.w;
  }

  uint32_t outd[4];
#pragma unroll
  for (int i4 = 0; i4 < 4; ++i4) {
    float vb[4];
#pragma unroll
    for (int ii = 0; ii < 4; ++ii) {
      int n = n0 + ns + i4 * 4 + ii;
      const float4* xr = (const float4*)(x + (size_t)n * 64);
      float acc = 0.f;
#pragma unroll
      for (int j = 0; j < 16; ++j) {
        float4 xv = xr[j];
        acc += xv.x * wr[4*j] + xv.y * wr[4*j+1] + xv.z * wr[4*j+2] + xv.w * wr[4*j+3];
      }
      vb[ii] = 64.f * rsqrtf(rowsum[n]) * acc;
    }
    outd[i4] = pk4(vb[0], vb[1], vb[2], vb[3]);
  }
  uint4 v; v.x = outd[0]; v.y = outd[1]; v.z = outd[2]; v.w = outd[3];
  *(uint4*)(Zt + (size_t)f * NN + n0 + ns) = v;
}

// ---------------------------------------------------------------------------
// K3/K5: fp8 GEMM  D[m][f] = sum_k A[m][k] * B[f][k]   (B has 64 rows)
// Tile 32(m) x 128(k), 256 threads / 4 waves, wave owns 16 f-cols, 2 m-tiles.
// mfma_f32_16x16x32_fp8_fp8; register-prefetch pipeline over LDS staging.
// mode 0: store fp32 partial to Out + blockIdx.y*M*64   (pass B, split-K=2)
// mode 1: out[n][f] = rsqrt(rowsum[n]) * acc / 8192 + bias[f]   (pass C)
// ---------------------------------------------------------------------------
__global__ __launch_bounds__(256) void k_gemm(
    const uint8_t* __restrict__ A,   // [M][K] fp8
    const uint8_t* __restrict__ B,   // [64][K] fp8
    float* __restrict__ Out,
    const float* __restrict__ rowsum,
    const float* __restrict__ bias,
    int M, int K, int mode)
{
  __shared__ uint8_t Al[32 * 128];
  __shared__ uint8_t Bl[64 * 128];

  const int t    = threadIdx.x;
  const int lane = t & 63;
  const int wv   = t >> 6;
  const int m0   = blockIdx.x * 32;
  const int kchunk = K / gridDim.y;
  const int k0   = blockIdx.y * kchunk;
  const int iters = kchunk >> 7;

  const int r  = lane & 15;
  const int q  = lane >> 4;
  const int f0 = wv * 16;

  const int arow = t >> 3;          // 0..31
  const int aoff = (t & 7) * 16;

  const uint8_t* Ag  = A + (size_t)(m0 + arow) * K + k0 + aoff;
  const uint8_t* Bg0 = B + (size_t)arow * K + k0 + aoff;
  const uint8_t* Bg1 = B + (size_t)(arow + 32) * K + k0 + aoff;

  v4f acc0 = {0.f, 0.f, 0.f, 0.f};
  v4f acc1 = {0.f, 0.f, 0.f, 0.f};

  uint4 av  = *(const uint4*)Ag;
  uint4 bv0 = *(const uint4*)Bg0;
  uint4 bv1 = *(const uint4*)Bg1;

  for (int kt = 0; kt < iters; ++kt) {
    __syncthreads();
    *(uint4*)&Al[t * 16]        = av;
    *(uint4*)&Bl[t * 16]        = bv0;
    *(uint4*)&Bl[4096 + t * 16] = bv1;
    __syncthreads();
    if (kt + 1 < iters) {                 // prefetch next tile during MFMAs
      const int o = (kt + 1) * 128;
      av  = *(const uint4*)(Ag + o);
      bv0 = *(const uint4*)(Bg0 + o);
      bv1 = *(const uint4*)(Bg1 + o);
    }
#pragma unroll
    for (int ks = 0; ks < 4; ++ks) {
      long bfrag  = *(const long*)&Bl[(f0 + r) * 128 + ks * 32 + q * 8];
      long afrag0 = *(const long*)&Al[(r)      * 128 + ks * 32 + q * 8];
      long afrag1 = *(const long*)&Al[(16 + r) * 128 + ks * 32 + q * 8];
      acc0 = __builtin_amdgcn_mfma_f32_16x16x32_fp8_fp8(afrag0, bfrag, acc0, 0, 0, 0);
      acc1 = __builtin_amdgcn_mfma_f32_16x16x32_fp8_fp8(afrag1, bfrag, acc1, 0, 0, 0);
    }
  }

  if (mode == 0) {
    float* U = Out + (size_t)blockIdx.y * M * 64;
#pragma unroll
    for (int i = 0; i < 4; ++i) {
      U[(size_t)(m0 + 4 * q + i) * 64 + f0 + r]      = acc0[i];
      U[(size_t)(m0 + 16 + 4 * q + i) * 64 + f0 + r] = acc1[i];
    }
  } else {
#pragma unroll
    for (int i = 0; i < 4; ++i) {
      int na = m0 + 4 * q + i;
      int nb = m0 + 16 + 4 * q + i;
      Out[(size_t)na * 64 + f0 + r] =
          rsqrtf(rowsum[na]) * acc0[i] * (1.f / 8192.f) + bias[f0 + r];
      Out[(size_t)nb * 64 + f0 + r] =
          rsqrtf(rowsum[nb]) * acc1[i] * (1.f / 8192.f) + bias[f0 + r];
    }
  }
}

// ---------------------------------------------------------------------------
// K4: Yt[f][e] = fp8( 128 * W[e] / colsum[e] * (U0+U1)[e][f] )  (= 8192*y_true)
// transposed through small LDS tile.
// ---------------------------------------------------------------------------
__global__ __launch_bounds__(256) void k_y(
    const float* __restrict__ Upart,
    const float* __restrict__ W,
    const float* __restrict__ colsum,
    uint8_t* __restrict__ Yt)
{
  __shared__ uint8_t TY[64 * 80];   // [f][e_local], stride 80 (16B aligned rows)
  const int t  = threadIdx.x;
  const int e0 = blockIdx.x * 64;
  const int el = t >> 2;
  const int c4 = (t & 3) * 16;
  const int e  = e0 + el;
  const float sc = 128.f * W[e] / colsum[e];
  const float4* u0 = (const float4*)(Upart + (size_t)e * 64 + c4);
  const float4* u1 = (const float4*)(Upart + (size_t)EE * 64 + (size_t)e * 64 + c4);
#pragma unroll
  for (int j = 0; j < 4; ++j) {
    float4 a = u0[j], b = u1[j];
    uint32_t dw = pk4(sc * (a.x + b.x), sc * (a.y + b.y),
                      sc * (a.z + b.z), sc * (a.w + b.w));
    TY[(size_t)(c4 + 4 * j + 0) * 80 + el] = (uint8_t)(dw);
    TY[(size_t)(c4 + 4 * j + 1) * 80 + el] = (uint8_t)(dw >> 8);
    TY[(size_t)(c4 + 4 * j + 2) * 80 + el] = (uint8_t)(dw >> 16);
    TY[(size_t)(c4 + 4 * j + 3) * 80 + el] = (uint8_t)(dw >> 24);
  }
  __syncthreads();
  const int f  = t >> 2;
  const int ec = (t & 3) * 16;
  uint4 v = *(const uint4*)&TY[(size_t)f * 80 + ec];
  *(uint4*)(Yt + (size_t)f * EE + e0 + ec) = v;
}

// ---------------------------------------------------------------------------
extern "C" void kernel_launch(void* const* d_in, const int* in_sizes, int n_in,
                              void* d_out, int out_size, void* d_ws, size_t ws_size,
                              hipStream_t stream) {
  const float* x      = (const float*)d_in[0];
  const float* H      = (const float*)d_in[1];
  const float* W      = (const float*)d_in[2];
  const float* weight = (const float*)d_in[3];
  const float* bias   = (const float*)d_in[4];
  float* out          = (float*)d_out;

  uint8_t* ws   = (uint8_t*)d_ws;
  uint8_t* Hn8  = ws;                                   // 134,217,728
  uint8_t* H8T  = ws + (size_t)NN * EE;                 // 134,217,728
  float*  rowsum = (float*)(ws + 2ull * NN * EE);       // 65,536
  float*  colsum = rowsum + NN;                         // 32,768
  uint8_t* Zt   = (uint8_t*)(colsum + EE);              // 1,048,576
  uint8_t* Yt   = Zt + (size_t)64 * NN;                 // 524,288
  float*  Upart = (float*)(Yt + (size_t)64 * EE);       // 4,194,304  (~262 MiB total)

  hipMemsetAsync(rowsum, 0, (NN + EE) * sizeof(float), stream);

  k_prep_h<<<dim3(32, 256), 256, 0, stream>>>(H, Hn8, H8T, rowsum, colsum);
  k_z<<<dim3(256), 256, 0, stream>>>(x, weight, rowsum, Zt);
  // pass B: U[e][f] = sum_n H[n][e] * z[n][f]; A = H8T [E][N], K = N, split-K = 2
  k_gemm<<<dim3(256, 2), 256, 0, stream>>>(H8T, Zt, Upart, rowsum, bias, EE, NN, 0);
  k_y<<<dim3(128), 256, 0, stream>>>(Upart, W, colsum, Yt);
  // pass C: out[n][f] = dv[n] * sum_e H[n][e] * y[e][f] + bias; A = Hn8 [N][E], K = E
  k_gemm<<<dim3(512, 1), 256, 0, stream>>>(Hn8, Yt, out, rowsum, bias, NN, EE, 1);
}

// Round 2
// 847.926 us; speedup vs baseline: 1.3239x; 1.3239x over previous
//
#include <hip/hip_runtime.h>
#include <stdint.h>

#define NN 16384
#define EE 8192
#define FT 64

typedef float v4f __attribute__((ext_vector_type(4)));

__device__ __forceinline__ uint32_t prm(uint32_t hi, uint32_t lo, uint32_t sel) {
  return __builtin_amdgcn_perm(hi, lo, sel);
}

// pack 4 floats -> 4 fp8 e4m3 bytes (byte0 = a .. byte3 = d)
__device__ __forceinline__ uint32_t pk4(float a, float b, float c, float d) {
  uint32_t lo = __builtin_amdgcn_cvt_pk_fp8_f32(a, b, 0, false);
  return __builtin_amdgcn_cvt_pk_fp8_f32(c, d, lo, true);
}

// async global->LDS, 16B per lane; LDS dest = wave-uniform base + lane*16
__device__ __forceinline__ void gl_lds16(const uint8_t* g, uint8_t* l) {
  __builtin_amdgcn_global_load_lds(
      (const __attribute__((address_space(1))) void*)g,
      (__attribute__((address_space(3))) void*)l, 16, 0, 0);
}

// ---------------------------------------------------------------------------
// K1: stream H (fp32) once -> rowsum, colsum, Hn8 [N][E] fp8, H8T [E][N] fp8.
// 64 n-rows x 256 e-cols per block; in-register 4x4 byte transpose (v_perm),
// staged through padded LDS. H8T writeout: 4 lanes cover 64B contiguous/row.
// ---------------------------------------------------------------------------
__global__ __launch_bounds__(256) void k_prep_h(
    const float* __restrict__ H,
    uint8_t* __restrict__ Hn8,
    uint8_t* __restrict__ H8T,
    float* __restrict__ rowsum,
    float* __restrict__ colsum)
{
  __shared__ uint8_t T8[256 * 68];   // [e_local][64 n + 4 pad]
  __shared__ float csumL[256];

  const int t    = threadIdx.x;
  const int lane = t & 63;
  const int wv   = t >> 6;
  const int e0   = blockIdx.x * 256;
  const int n0   = blockIdx.y * 64;

  csumL[t] = 0.f;
  __syncthreads();

  float cs0 = 0.f, cs1 = 0.f, cs2 = 0.f, cs3 = 0.f;

  for (int m = 0; m < 4; ++m) {
    const int g = wv + 4 * m;            // row-group 0..15 (wave-private)
    float4 r[4];
#pragma unroll
    for (int i = 0; i < 4; ++i) {
      const float* p = H + (size_t)(n0 + 4 * g + i) * EE + e0 + 4 * lane;
      r[i] = *(const float4*)p;
    }
    uint32_t D[4];
#pragma unroll
    for (int i = 0; i < 4; ++i) {
      cs0 += r[i].x; cs1 += r[i].y; cs2 += r[i].z; cs3 += r[i].w;
      float rsv = r[i].x + r[i].y + r[i].z + r[i].w;
#pragma unroll
      for (int s = 1; s < 64; s <<= 1) rsv += __shfl_xor(rsv, s);
      if (lane == 0) atomicAdd(&rowsum[n0 + 4 * g + i], rsv);
      D[i] = pk4(r[i].x, r[i].y, r[i].z, r[i].w);
      *(uint32_t*)(Hn8 + (size_t)(n0 + 4 * g + i) * EE + e0 + 4 * lane) = D[i];
    }
    uint32_t lo01 = prm(D[1], D[0], 0x05010400u);
    uint32_t hi01 = prm(D[1], D[0], 0x07030602u);
    uint32_t lo23 = prm(D[3], D[2], 0x05010400u);
    uint32_t hi23 = prm(D[3], D[2], 0x07030602u);
    uint32_t T0 = prm(lo23, lo01, 0x05040100u);
    uint32_t T1 = prm(lo23, lo01, 0x07060302u);
    uint32_t T2 = prm(hi23, hi01, 0x05040100u);
    uint32_t T3 = prm(hi23, hi01, 0x07060302u);
    *(uint32_t*)&T8[(size_t)(4 * lane + 0) * 68 + 4 * g] = T0;
    *(uint32_t*)&T8[(size_t)(4 * lane + 1) * 68 + 4 * g] = T1;
    *(uint32_t*)&T8[(size_t)(4 * lane + 2) * 68 + 4 * g] = T2;
    *(uint32_t*)&T8[(size_t)(4 * lane + 3) * 68 + 4 * g] = T3;
  }

  atomicAdd(&csumL[4 * lane + 0], cs0);
  atomicAdd(&csumL[4 * lane + 1], cs1);
  atomicAdd(&csumL[4 * lane + 2], cs2);
  atomicAdd(&csumL[4 * lane + 3], cs3);
  __syncthreads();
  atomicAdd(&colsum[e0 + t], csumL[t]);

  // H8T writeout: thread t -> (e_local = t>>2 + 64*jj, 16B n-chunk t&3);
  // 4 consecutive lanes = 64B contiguous per row.
  const int ec = t >> 2;
  const int nc = (t & 3) * 16;
#pragma unroll
  for (int jj = 0; jj < 4; ++jj) {
    const int el = ec + 64 * jj;
    uint4 v = *(const uint4*)&T8[(size_t)el * 68 + nc];
    *(uint4*)(H8T + (size_t)(e0 + el) * NN + n0 + nc) = v;
  }
}

// ---------------------------------------------------------------------------
// K2: Zt[f][n] = fp8( 64 * rsqrt(rowsum[n]) * (x @ weight)[n][f] )
// ---------------------------------------------------------------------------
__global__ __launch_bounds__(256) void k_z(
    const float* __restrict__ x,
    const float* __restrict__ weight,
    const float* __restrict__ rowsum,
    uint8_t* __restrict__ Zt)
{
  __shared__ float wT[64 * 68];
  const int t  = threadIdx.x;
  const int n0 = blockIdx.x * 64;
  for (int i = t; i < 4096; i += 256) {
    int cc = i >> 6, ff = i & 63;
    wT[ff * 68 + cc] = weight[i];
  }
  __syncthreads();

  const int f  = t >> 2;
  const int ns = (t & 3) * 16;

  float wr[64];
#pragma unroll
  for (int j = 0; j < 16; ++j) {
    float4 w4 = *(const float4*)&wT[f * 68 + 4 * j];
    wr[4*j] = w4.x; wr[4*j+1] = w4.y; wr[4*j+2] = w4.z; wr[4*j+3] = w4.w;
  }

  uint32_t outd[4];
#pragma unroll
  for (int i4 = 0; i4 < 4; ++i4) {
    float vb[4];
#pragma unroll
    for (int ii = 0; ii < 4; ++ii) {
      int n = n0 + ns + i4 * 4 + ii;
      const float4* xr = (const float4*)(x + (size_t)n * 64);
      float acc = 0.f;
#pragma unroll
      for (int j = 0; j < 16; ++j) {
        float4 xv = xr[j];
        acc += xv.x * wr[4*j] + xv.y * wr[4*j+1] + xv.z * wr[4*j+2] + xv.w * wr[4*j+3];
      }
      vb[ii] = 64.f * rsqrtf(rowsum[n]) * acc;
    }
    outd[i4] = pk4(vb[0], vb[1], vb[2], vb[3]);
  }
  uint4 v; v.x = outd[0]; v.y = outd[1]; v.z = outd[2]; v.w = outd[3];
  *(uint4*)(Zt + (size_t)f * NN + n0 + ns) = v;
}

// ---------------------------------------------------------------------------
// GEMM: D[m][f] = sum_k A[m][k]*B[f][k], fp8, F=64. Tile 128m x 256k.
// global_load_lds (16B) staging with XOR chunk swizzle (chunk c at slot
// c^(row&7)) -> conflict-free ds_read_b64 fragment reads. 256 thr / 4 waves;
// wave w owns m-rows [w*32, w*32+32) x all 64 f = 8 accs, 64 MFMA / k-tile.
// Split-K partials (fp32) to Out + blockIdx.y*M*64.
// ---------------------------------------------------------------------------
__global__ __launch_bounds__(256) void k_gemm2(
    const uint8_t* __restrict__ A,   // [M][K] fp8
    const uint8_t* __restrict__ B,   // [64][K] fp8
    float* __restrict__ Out,
    int M, int K, int kchunk)
{
  __shared__ uint8_t Al[128 * 256];
  __shared__ uint8_t Bl[64 * 256];

  const int t    = threadIdx.x;
  const int lane = t & 63;
  const int wv   = t >> 6;
  const int m0   = blockIdx.x * 128;
  const int k0   = blockIdx.y * kchunk;
  const int iters = kchunk >> 8;

  const int r = lane & 15;
  const int q = lane >> 4;

  // loader mapping: per instr, 64 lanes = 4 rows x 16 chunks (16B each)
  const int lr = lane >> 4;     // row within instr group
  const int sl = lane & 15;     // LDS chunk slot within row

  const uint8_t* aptr[8];
  const uint8_t* bptr[4];
  uint8_t* aldst[8];
  uint8_t* bldst[4];
#pragma unroll
  for (int i = 0; i < 8; ++i) {
    int rA = wv * 32 + i * 4 + lr;
    int c  = sl ^ (rA & 7);
    aptr[i]  = A + (size_t)(m0 + rA) * K + k0 + c * 16;
    aldst[i] = &Al[(wv * 32 + i * 4) * 256];
  }
#pragma unroll
  for (int i = 0; i < 4; ++i) {
    int rB = wv * 16 + i * 4 + lr;
    int c  = sl ^ (rB & 7);
    bptr[i]  = B + (size_t)rB * K + k0 + c * 16;
    bldst[i] = &Bl[(wv * 16 + i * 4) * 256];
  }

  v4f acc[2][4];
#pragma unroll
  for (int mt = 0; mt < 2; ++mt)
#pragma unroll
    for (int ft = 0; ft < 4; ++ft)
      acc[mt][ft] = (v4f){0.f, 0.f, 0.f, 0.f};

  for (int kt = 0; kt < iters; ++kt) {
    __syncthreads();
    const size_t ko = (size_t)kt * 256;
#pragma unroll
    for (int i = 0; i < 8; ++i) gl_lds16(aptr[i] + ko, aldst[i]);
#pragma unroll
    for (int i = 0; i < 4; ++i) gl_lds16(bptr[i] + ko, bldst[i]);
    __syncthreads();
#pragma unroll
    for (int ks = 0; ks < 8; ++ks) {
      const int ch = ks * 2 + (q >> 1);
      const int h8 = (q & 1) * 8;
      long bfr[4], afr[2];
#pragma unroll
      for (int ft = 0; ft < 4; ++ft) {
        int rb = ft * 16 + r;
        bfr[ft] = *(const long*)&Bl[rb * 256 + ((ch ^ (rb & 7)) * 16) + h8];
      }
#pragma unroll
      for (int mt = 0; mt < 2; ++mt) {
        int ra = wv * 32 + mt * 16 + r;
        afr[mt] = *(const long*)&Al[ra * 256 + ((ch ^ (ra & 7)) * 16) + h8];
      }
#pragma unroll
      for (int mt = 0; mt < 2; ++mt)
#pragma unroll
        for (int ft = 0; ft < 4; ++ft)
          acc[mt][ft] = __builtin_amdgcn_mfma_f32_16x16x32_fp8_fp8(
              afr[mt], bfr[ft], acc[mt][ft], 0, 0, 0);
    }
  }

  float* U = Out + (size_t)blockIdx.y * M * 64;
#pragma unroll
  for (int mt = 0; mt < 2; ++mt)
#pragma unroll
    for (int ft = 0; ft < 4; ++ft)
#pragma unroll
      for (int i = 0; i < 4; ++i)
        U[(size_t)(m0 + wv * 32 + mt * 16 + 4 * q + i) * 64 + ft * 16 + r] =
            acc[mt][ft][i];
}

// ---------------------------------------------------------------------------
// K4: Yt[f][e] = fp8( 128 * W[e]/colsum[e] * sum_{p<8} Upart[p][e][f] )
// ---------------------------------------------------------------------------
__global__ __launch_bounds__(256) void k_y(
    const float* __restrict__ Upart,
    const float* __restrict__ W,
    const float* __restrict__ colsum,
    uint8_t* __restrict__ Yt)
{
  __shared__ uint8_t TY[64 * 80];
  const int t  = threadIdx.x;
  const int e0 = blockIdx.x * 64;
  const int el = t >> 2;
  const int c4 = (t & 3) * 16;
  const int e  = e0 + el;
  const float sc = 128.f * W[e] / colsum[e];

  float s[16];
#pragma unroll
  for (int j = 0; j < 16; ++j) s[j] = 0.f;
  for (int p = 0; p < 8; ++p) {
    const float4* u = (const float4*)(Upart + ((size_t)p * EE + e) * 64 + c4);
#pragma unroll
    for (int j = 0; j < 4; ++j) {
      float4 a = u[j];
      s[4*j+0] += a.x; s[4*j+1] += a.y; s[4*j+2] += a.z; s[4*j+3] += a.w;
    }
  }
#pragma unroll
  for (int j = 0; j < 4; ++j) {
    uint32_t dw = pk4(sc * s[4*j], sc * s[4*j+1], sc * s[4*j+2], sc * s[4*j+3]);
    TY[(size_t)(c4 + 4 * j + 0) * 80 + el] = (uint8_t)(dw);
    TY[(size_t)(c4 + 4 * j + 1) * 80 + el] = (uint8_t)(dw >> 8);
    TY[(size_t)(c4 + 4 * j + 2) * 80 + el] = (uint8_t)(dw >> 16);
    TY[(size_t)(c4 + 4 * j + 3) * 80 + el] = (uint8_t)(dw >> 24);
  }
  __syncthreads();
  const int f  = t >> 2;
  const int ec = (t & 3) * 16;
  uint4 v = *(const uint4*)&TY[(size_t)f * 80 + ec];
  *(uint4*)(Yt + (size_t)f * EE + e0 + ec) = v;
}

// ---------------------------------------------------------------------------
// K6: out[n][f] = rsqrt(rowsum[n]) * (sum_{p<4} Vpart[p][n][f]) / 8192 + bias
// ---------------------------------------------------------------------------
__global__ __launch_bounds__(256) void k_out(
    const float* __restrict__ Vpart,
    const float* __restrict__ rowsum,
    const float* __restrict__ bias,
    float* __restrict__ out)
{
  const int t  = threadIdx.x;
  const int n  = blockIdx.x * 64 + (t >> 2);
  const int c4 = (t & 3) * 16;
  float s[16];
#pragma unroll
  for (int j = 0; j < 16; ++j) s[j] = 0.f;
#pragma unroll
  for (int p = 0; p < 4; ++p) {
    const float4* v = (const float4*)(Vpart + ((size_t)p * NN + n) * 64 + c4);
#pragma unroll
    for (int j = 0; j < 4; ++j) {
      float4 a = v[j];
      s[4*j+0] += a.x; s[4*j+1] += a.y; s[4*j+2] += a.z; s[4*j+3] += a.w;
    }
  }
  const float dv = rsqrtf(rowsum[n]) * (1.f / 8192.f);
  float4* o = (float4*)(out + (size_t)n * 64 + c4);
#pragma unroll
  for (int j = 0; j < 4; ++j) {
    float4 bb = *(const float4*)(bias + c4 + 4 * j);
    float4 rr;
    rr.x = s[4*j+0] * dv + bb.x;
    rr.y = s[4*j+1] * dv + bb.y;
    rr.z = s[4*j+2] * dv + bb.z;
    rr.w = s[4*j+3] * dv + bb.w;
    o[j] = rr;
  }
}

// ---------------------------------------------------------------------------
extern "C" void kernel_launch(void* const* d_in, const int* in_sizes, int n_in,
                              void* d_out, int out_size, void* d_ws, size_t ws_size,
                              hipStream_t stream) {
  const float* x      = (const float*)d_in[0];
  const float* H      = (const float*)d_in[1];
  const float* W      = (const float*)d_in[2];
  const float* weight = (const float*)d_in[3];
  const float* bias   = (const float*)d_in[4];
  float* out          = (float*)d_out;

  uint8_t* ws    = (uint8_t*)d_ws;
  uint8_t* Hn8   = ws;                                   // 128 MiB
  uint8_t* H8T   = ws + (size_t)NN * EE;                 // 128 MiB
  float*  rowsum = (float*)(ws + 2ull * NN * EE);        // 64 KiB
  float*  colsum = rowsum + NN;                          // 32 KiB
  uint8_t* Zt    = (uint8_t*)(colsum + EE);              // 1 MiB
  uint8_t* Yt    = Zt + (size_t)64 * NN;                 // 0.5 MiB
  float*  Upart  = (float*)(Yt + (size_t)64 * EE);       // 8 parts x 2 MiB
  float*  Vpart  = Upart + 8ull * EE * 64;               // 4 parts x 4 MiB

  hipMemsetAsync(rowsum, 0, (NN + EE) * sizeof(float), stream);

  k_prep_h<<<dim3(32, 256), 256, 0, stream>>>(H, Hn8, H8T, rowsum, colsum);
  k_z<<<dim3(256), 256, 0, stream>>>(x, weight, rowsum, Zt);
  // pass B: U[e][f] = sum_n H8T[e][n] * Zt[f][n]; M=EE, K=NN, split-K=8
  k_gemm2<<<dim3(64, 8), 256, 0, stream>>>(H8T, Zt, Upart, EE, NN, NN / 8);
  k_y<<<dim3(128), 256, 0, stream>>>(Upart, W, colsum, Yt);
  // pass C: V[n][f] = sum_e Hn8[n][e] * Yt[f][e]; M=NN, K=EE, split-K=4
  k_gemm2<<<dim3(128, 4), 256, 0, stream>>>(Hn8, Yt, Vpart, NN, EE, EE / 4);
  k_out<<<dim3(256), 256, 0, stream>>>(Vpart, rowsum, bias, out);
}